// Round 7
// baseline (155.760 us; speedup 1.0000x reference)
//
#include <hip/hip_runtime.h>
#include <hip/hip_bf16.h>

// Problem constants
#define B_  64
#define N_  4096
#define F_  64
#define H1_ 128
#define H2_ 128

#define GRID_ 512           // 512 blocks x 512 rows, 2 blocks/CU resident
#define TPB_  512           // 8 waves; each wave owns 64 rows (4 rounds of 16)

typedef __attribute__((ext_vector_type(8))) short bf16x8;   // 8 bf16 (4 VGPRs)
typedef __attribute__((ext_vector_type(4))) float f32x4;    // MFMA accumulator

// pack two f32 -> u32 of 2 bf16 (RNE); compiler emits v_cvt_pk_bf16_f32
__device__ __forceinline__ unsigned int cvtpk(float lo, float hi) {
    __hip_bfloat162 h = __float22bfloat162_rn(make_float2(lo, hi));
    union { __hip_bfloat162 h; unsigned int u; } c; c.h = h; return c.u;
}

// ---------------------------------------------------------------------------
// Fused MLP -> exp(masked logits) -> per-batch sum.
// 512-thr blocks (8 waves), W1+W2 in swizzled LDS, ZERO per-round LDS
// round-trip: H1 redistribution (MFMA C-layout -> next A-layout) done
// in-register with 32 ds_bpermute (__shfl) + 16 cndmask per 16-row round.
//   L1 swapped:  C1 = mfma(W1^T-frag, X^T-frag): lane(lg,lr) holds
//                H1[h1=hb*16+lg*4+j][row=lr]  -> pack pairs q[hb][jj]
//   transpose:   a2-u32 w of frag ks needs h1=ks*32+lg*8+2w -> from lane
//                src=(lg&1)*32+(w>>1)*16+lr, reg q[2ks+(lg>>1)][w&1]
//                (bit5 of target selects q-row => A/B shfl + cndmask)
//   L2 standard: C2 = mfma(a2, W2^T-frag from LDS)
// XOR swizzle byte^=(row&7)<<4 on both LDS arrays => conflict-free b128.
// ---------------------------------------------------------------------------
__global__ __launch_bounds__(TPB_, 4) void mlp_kernel(
    const float* __restrict__ x,
    const int*   __restrict__ mask,
    const float* __restrict__ W1,    // [F=64][H1=128] f32
    const float* __restrict__ b1,
    const float* __restrict__ W2,    // [H1=128][H2=128] f32
    const float* __restrict__ b2,
    const float* __restrict__ W3,
    const float* __restrict__ b3,
    float* __restrict__ eout,        // exp(tns) per row
    float* __restrict__ sums)        // [B] batch exp-sums (pre-zeroed)
{
    __shared__ unsigned short W1s[128][64];    // [h1][f]  swizzled (16 KB)
    __shared__ unsigned short W2s[128][128];   // [h2][h1] swizzled (32 KB)
    __shared__ float b1s[128];
    __shared__ float b2s[128];
    __shared__ float w3s[128];                 // total ~50.2 KB -> 2 blk/CU

    const int t    = threadIdx.x;
    const int wave = t >> 6;
    const int lane = t & 63;
    const int lr   = lane & 15;
    const int lg   = lane >> 4;

    // ---- stage W1^T [h1][f] bf16, swizzled (one-time) ----
    {
        const int h1  = t >> 2, seg = t & 3;      // seg: 16 f-columns each
        const int swz = (h1 & 7) << 4;
        float v[16];
        #pragma unroll
        for (int i = 0; i < 16; ++i)
            v[i] = W1[(size_t)(seg * 16 + i) * 128 + h1];
        uint4 u0 = make_uint4(cvtpk(v[0], v[1]),  cvtpk(v[2], v[3]),
                              cvtpk(v[4], v[5]),  cvtpk(v[6], v[7]));
        uint4 u1 = make_uint4(cvtpk(v[8], v[9]),  cvtpk(v[10], v[11]),
                              cvtpk(v[12], v[13]), cvtpk(v[14], v[15]));
        char* base = (char*)&W1s[h1][0];
        *(uint4*)(base + ((seg * 32 +  0) ^ swz)) = u0;
        *(uint4*)(base + ((seg * 32 + 16) ^ swz)) = u1;
    }
    // ---- stage W2^T [h2][h1] bf16, swizzled (one-time) ----
    {
        const int h2  = t >> 2, seg = t & 3;      // seg: 32 h1-columns each
        const int swz = (h2 & 7) << 4;
        char* base = (char*)&W2s[h2][0];
        #pragma unroll
        for (int g = 0; g < 4; ++g) {
            float v[8];
            #pragma unroll
            for (int i = 0; i < 8; ++i)
                v[i] = W2[(size_t)(seg * 32 + g * 8 + i) * 128 + h2];
            uint4 u = make_uint4(cvtpk(v[0], v[1]), cvtpk(v[2], v[3]),
                                 cvtpk(v[4], v[5]), cvtpk(v[6], v[7]));
            *(uint4*)(base + (((seg * 32 + g * 8) * 2) ^ swz)) = u;
        }
    }
    if (t < 128) { b1s[t] = b1[t]; b2s[t] = b2[t]; w3s[t] = W3[t]; }
    const float b3v = b3[0];
    __syncthreads();                  // the only block-wide barrier

    const int rbw     = blockIdx.x * 512 + wave * 64;   // wave's 64 rows
    const int swzr    = (lr & 7) << 4;
    const int srcl0   = ((lane >> 4) & 1) * 32 + lr;    // transpose src lanes
    const int srcl1   = srcl0 + 16;
    const bool lo32   = lane < 32;

    // ---- x for round 0 ----
    float4 xf[2][2];
    #pragma unroll
    for (int ks = 0; ks < 2; ++ks) {
        const float4* p = (const float4*)(x + (size_t)(rbw + lr) * 64 + ks * 32 + lg * 8);
        xf[ks][0] = p[0];
        xf[ks][1] = p[1];
    }

    float  ssum = 0.0f;
    bf16x8 a2[2][4];
    int4   mk0, mk1;

    #pragma unroll
    for (int r = 0; r < 4; ++r) {
        // mask for this group's epilogue (issued at group start, used ~end)
        if (!(r & 1) && lr == 0) {
            const int gb = rbw + (r >> 1) * 32;
            mk0 = *(const int4*)&mask[gb + lg * 4];
            mk1 = *(const int4*)&mask[gb + 16 + lg * 4];
        }

        // ---- pack current x (frees xf), then prefetch next round into xf ----
        bf16x8 xb[2];
        #pragma unroll
        for (int ks = 0; ks < 2; ++ks) {
            float4 a = xf[ks][0], b = xf[ks][1];
            union { uint4 u; bf16x8 b; } c;
            c.u = make_uint4(cvtpk(a.x, a.y), cvtpk(a.z, a.w),
                             cvtpk(b.x, b.y), cvtpk(b.z, b.w));
            xb[ks] = c.b;
        }
        if (r < 3) {
            #pragma unroll
            for (int ks = 0; ks < 2; ++ks) {
                const float4* p = (const float4*)(x + (size_t)(rbw + (r + 1) * 16 + lr) * 64 + ks * 32 + lg * 8);
                xf[ks][0] = p[0];
                xf[ks][1] = p[1];
            }
        }

        // ---- layer 1: C1[h1=128][row=16], W1 frags from LDS ----
        f32x4 acc[8];
        #pragma unroll
        for (int hb = 0; hb < 8; ++hb)
            acc[hb] = *(const f32x4*)&b1s[hb * 16 + lg * 4];
        #pragma unroll
        for (int ks = 0; ks < 2; ++ks)
            #pragma unroll
            for (int hb = 0; hb < 8; ++hb) {
                const char* bp = (const char*)&W1s[hb * 16 + lr][0]
                               + ((ks * 64 + lg * 16) ^ swzr);
                bf16x8 w1f = *(const bf16x8*)bp;
                acc[hb] = __builtin_amdgcn_mfma_f32_16x16x32_bf16(w1f, xb[ks], acc[hb], 0, 0, 0);
            }

        // ---- relu -> packed bf16 pairs q[hb][jj] ----
        unsigned int q[8][2];
        #pragma unroll
        for (int hb = 0; hb < 8; ++hb) {
            q[hb][0] = cvtpk(fmaxf(acc[hb][0], 0.0f), fmaxf(acc[hb][1], 0.0f));
            q[hb][1] = cvtpk(fmaxf(acc[hb][2], 0.0f), fmaxf(acc[hb][3], 0.0f));
        }

        // ---- in-wave transpose -> a2[r&1] (32 bpermute + 16 cndmask) ----
        #pragma unroll
        for (int ks = 0; ks < 4; ++ks) {
            unsigned int A0 = __shfl(q[2 * ks][0],     srcl0, 64);
            unsigned int B0 = __shfl(q[2 * ks + 1][0], srcl0, 64);
            unsigned int A1 = __shfl(q[2 * ks][1],     srcl0, 64);
            unsigned int B1 = __shfl(q[2 * ks + 1][1], srcl0, 64);
            unsigned int A2 = __shfl(q[2 * ks][0],     srcl1, 64);
            unsigned int B2 = __shfl(q[2 * ks + 1][0], srcl1, 64);
            unsigned int A3 = __shfl(q[2 * ks][1],     srcl1, 64);
            unsigned int B3 = __shfl(q[2 * ks + 1][1], srcl1, 64);
            union { uint4 u; bf16x8 b; } c;
            c.u = make_uint4(lo32 ? A0 : B0, lo32 ? A1 : B1,
                             lo32 ? A2 : B2, lo32 ? A3 : B3);
            a2[r & 1][ks] = c.b;
        }

        // ---- every 2 rounds: W2 pass over 32 rows + epilogue ----
        if (r & 1) {
            const int g = r >> 1;
            float p[2][4];
            #pragma unroll
            for (int mb = 0; mb < 2; ++mb)
                #pragma unroll
                for (int j = 0; j < 4; ++j) p[mb][j] = 0.0f;

            #pragma unroll
            for (int hb = 0; hb < 8; ++hb) {
                bf16x8 wf[4];
                #pragma unroll
                for (int ks = 0; ks < 4; ++ks) {
                    const char* bp = (const char*)&W2s[hb * 16 + lr][0]
                                   + (((ks * 32 + lg * 8) * 2) ^ swzr);
                    wf[ks] = *(const bf16x8*)bp;
                }
                const float b2v = b2s[hb * 16 + lr];
                const float w3v = w3s[hb * 16 + lr];
                f32x4 c2[2];
                #pragma unroll
                for (int mb = 0; mb < 2; ++mb) {
                    f32x4 ci = {b2v, b2v, b2v, b2v};
                    c2[mb] = ci;
                }
                #pragma unroll
                for (int ks = 0; ks < 4; ++ks)
                    #pragma unroll
                    for (int mb = 0; mb < 2; ++mb)
                        c2[mb] = __builtin_amdgcn_mfma_f32_16x16x32_bf16(
                                     a2[mb][ks], wf[ks], c2[mb], 0, 0, 0);
                #pragma unroll
                for (int mb = 0; mb < 2; ++mb)
                    #pragma unroll
                    for (int j = 0; j < 4; ++j)
                        p[mb][j] += fmaxf(c2[mb][j], 0.0f) * w3v;
            }

            // reduce over lr (h2 mod 16) — DPP xor shuffles
            #pragma unroll
            for (int msk = 1; msk < 16; msk <<= 1)
                #pragma unroll
                for (int mb = 0; mb < 2; ++mb)
                    #pragma unroll
                    for (int j = 0; j < 4; ++j)
                        p[mb][j] += __shfl_xor(p[mb][j], msk, 64);

            if (lr == 0) {                // rows g*32 + mb*16 + lg*4 .. +3
                const int r0 = rbw + g * 32 + lg * 4;
                float4 ev0, ev1;
                ev0.x = mk0.x ? expf(p[0][0] + b3v) : 0.0f;
                ev0.y = mk0.y ? expf(p[0][1] + b3v) : 0.0f;
                ev0.z = mk0.z ? expf(p[0][2] + b3v) : 0.0f;
                ev0.w = mk0.w ? expf(p[0][3] + b3v) : 0.0f;
                ev1.x = mk1.x ? expf(p[1][0] + b3v) : 0.0f;
                ev1.y = mk1.y ? expf(p[1][1] + b3v) : 0.0f;
                ev1.z = mk1.z ? expf(p[1][2] + b3v) : 0.0f;
                ev1.w = mk1.w ? expf(p[1][3] + b3v) : 0.0f;
                *(float4*)&eout[r0]      = ev0;
                *(float4*)&eout[r0 + 16] = ev1;
                ssum += ev0.x + ev0.y + ev0.z + ev0.w
                      + ev1.x + ev1.y + ev1.z + ev1.w;
            }
        }
    }

    // ---- one batch-sum atomic per wave (block's 512 rows in one batch) ----
    ssum += __shfl_xor(ssum, 16, 64);
    ssum += __shfl_xor(ssum, 32, 64);
    if (lane == 0) atomicAdd(&sums[blockIdx.x >> 3], ssum);
}

// ---------------------------------------------------------------------------
// out = e / sums[batch]
// ---------------------------------------------------------------------------
__global__ __launch_bounds__(256) void norm_kernel(
    const float* __restrict__ e, const float* __restrict__ sums,
    float* __restrict__ out)
{
    int i4 = blockIdx.x * 256 + threadIdx.x;       // 65536 float4s
    float4 v = ((const float4*)e)[i4];
    float inv = 1.0f / sums[i4 >> 10];             // 1024 float4 per batch
    v.x *= inv; v.y *= inv; v.z *= inv; v.w *= inv;
    ((float4*)out)[i4] = v;
}

// ---------------------------------------------------------------------------
extern "C" void kernel_launch(void* const* d_in, const int* in_sizes, int n_in,
                              void* d_out, int out_size, void* d_ws, size_t ws_size,
                              hipStream_t stream)
{
    const float* x    = (const float*)d_in[0];
    const int*   mask = (const int*)d_in[1];
    const float* W1   = (const float*)d_in[2];
    const float* b1   = (const float*)d_in[3];
    const float* W2   = (const float*)d_in[4];
    const float* b2   = (const float*)d_in[5];
    const float* W3   = (const float*)d_in[6];
    const float* b3   = (const float*)d_in[7];
    float* out = (float*)d_out;

    float* sums = (float*)d_ws;                          // 64 floats
    float* eout = (float*)((char*)d_ws + 1024);          // 1 MB

    hipMemsetAsync(sums, 0, B_ * sizeof(float), stream);
    mlp_kernel<<<GRID_, TPB_, 0, stream>>>(x, mask, W1, b1, W2, b2, W3, b3, eout, sums);
    norm_kernel<<<(B_ * N_ / 4) / 256, 256, 0, stream>>>(eout, sums, out);
}